// Round 17
// baseline (338.788 us; speedup 1.0000x reference)
//
#include <hip/hip_runtime.h>

typedef __attribute__((ext_vector_type(8))) short bf16x8;
typedef __attribute__((ext_vector_type(4))) float f32x4;
typedef unsigned short u16;
typedef unsigned int u32;

#define MFMA16(a, b, c) __builtin_amdgcn_mfma_f32_16x16x32_bf16((a), (b), (c), 0, 0, 0)
#define CFENCE() asm volatile("" ::: "memory")

// ROUND-17 BISECT. Evidence: every conv_w_k(d_ws wT) consumer failed
// (R1-R4, R16A; 1 AND 2 blk/CU); every non-consumer passed. R16 proved
// ws_size >= 262144 (fallback is verbatim-R15 and would have passed).
// This round: R15 VERBATIM except panels staged FROM wT (stage_wt) --
// panel content provably identical to R15's stage_h if wT is correct.
//   PASS(enc_stage_wt) -> wT handoff good; direct-global B-reads were the bug.
//   FAIL              -> d_ws weight handoff is broken, ban d_ws forever.
// Kernel names distinct so rocprof Kernel_Name identifies the path taken.
// INVARIANTS: LDS strides x8 u16 (136/72/264); 1 blk/CU (2-blk banned:
// R8/R9/R10 vs R11).

__device__ __forceinline__ u16 f2bf(float f) {
    union { float f; u32 u; } c; c.f = f;
    u32 r = c.u + 0x7fffu + ((c.u >> 16) & 1u);   // RNE
    return (u16)(r >> 16);
}

__device__ __forceinline__ bf16x8 pack8(f32x4 a, f32x4 b) {
    union { u32 w[4]; bf16x8 v; } r;
    asm("v_cvt_pk_bf16_f32 %0, %1, %2" : "=v"(r.w[0]) : "v"(a[0]), "v"(a[1]));
    asm("v_cvt_pk_bf16_f32 %0, %1, %2" : "=v"(r.w[1]) : "v"(a[2]), "v"(a[3]));
    asm("v_cvt_pk_bf16_f32 %0, %1, %2" : "=v"(r.w[2]) : "v"(b[0]), "v"(b[1]));
    asm("v_cvt_pk_bf16_f32 %0, %1, %2" : "=v"(r.w[3]) : "v"(b[2]), "v"(b[3]));
    return r.v;
}

// ---------------- weights: f32 -> bf16, transposed, into d_ws --------------
// wT: WQ[128][128]@0, WK@16384, WV@32768, WO@49152, W1T[256][128]@65536,
// W2T[128][256]@98304 (u16 offsets). WT[n][k] = W[k][n].
__global__ void conv_w_k(const float* __restrict__ Wq, const float* __restrict__ Wk,
                         const float* __restrict__ Wv, const float* __restrict__ Wo,
                         const float* __restrict__ W1, const float* __restrict__ W2,
                         u16* __restrict__ o) {
    int i = blockIdx.x * 256 + threadIdx.x;         // 131072 total
    float v;
    if (i < 16384)      { int j = i;         v = Wq[(j & 127) * 128 + (j >> 7)]; }
    else if (i < 32768) { int j = i - 16384; v = Wk[(j & 127) * 128 + (j >> 7)]; }
    else if (i < 49152) { int j = i - 32768; v = Wv[(j & 127) * 128 + (j >> 7)]; }
    else if (i < 65536) { int j = i - 49152; v = Wo[(j & 127) * 128 + (j >> 7)]; }
    else if (i < 98304) { int j = i - 65536; v = W1[(j & 127) * 256 + (j >> 7)]; }
    else                { int j = i - 98304; v = W2[(j & 255) * 128 + (j >> 8)]; }
    o[i] = f2bf(v);
}

// stage a [64][128] u16 half-panel from TRANSPOSED wT section (row stride ld):
// sW[n][k] = WT[(n0+n)*ld + k0+k]. Equivalence proof vs stage_h(W,...):
//   stage_h(W1,256,n0,k0): sW[n][k] = W1[(k0+k)*256 + n0+n]
//   stage_wt(W1T,128,n0,k0): sW[n][k] = W1T[(n0+n)*128 + k0+k]
//                                     = W1[(k0+k)*256 + n0+n]   (conv_w_k map)
//   -- identical; same for WQ/WK/WV/WO (ld 128) and W2T (ld 256).
__device__ __forceinline__ void stage_wt(const u16* __restrict__ WT, int ld,
                                         int n0, int k0, u16* __restrict__ sW,
                                         int t) {
#pragma unroll
    for (int i = 0; i < 2; ++i) {
        int e = i * 512 + t;                      // 0..1023
        int n = e & 63, c = e >> 6;               // c: 8-u16 chunk, 0..15
        uint4 pk = *(const uint4*)(WT + (size_t)(n0 + n) * ld + k0 + c * 8);
        *(uint4*)(sW + n * 136 + c * 8) = pk;     // 16B-aligned both sides
    }
}

// original f32-source staging (fallback path only)
__device__ __forceinline__ void stage_h(const float* __restrict__ W, int ld,
                                        int n0, int k0, u16* __restrict__ sW,
                                        int t) {
#pragma unroll
    for (int i = 0; i < 4; ++i) {
        int e = i * 512 + t;
        int n = e & 63, kq = e >> 6;
        const float* src = W + (size_t)(k0 + kq * 4) * ld + n0 + n;
        float a = src[0], b = src[ld], c = src[2 * ld], d = src[3 * ld];
        u32 lo, hi;
        asm("v_cvt_pk_bf16_f32 %0, %1, %2" : "=v"(lo) : "v"(a), "v"(b));
        asm("v_cvt_pk_bf16_f32 %0, %1, %2" : "=v"(hi) : "v"(c), "v"(d));
        uint2 pk; pk.x = lo; pk.y = hi;
        *(uint2*)(sW + n * 136 + kq * 4) = pk;
    }
}

__device__ __forceinline__ void gemm_h(const bf16x8 aF[4], const u16* __restrict__ sW,
                                       int lr, int lk, f32x4 acc[4]) {
#pragma unroll
    for (int ks = 0; ks < 4; ++ks)
#pragma unroll
        for (int nt = 0; nt < 4; ++nt) {
            bf16x8 b = *(const bf16x8*)(sW + (nt * 16 + lr) * 136 + ks * 32 + lk * 8);
            acc[nt] = MFMA16(aF[ks], b, acc[nt]);
        }
}

// MFMA 16x16x32 bf16 (pinned: learn_hip m89/m91/m97): A row=lane&15,
// k=(lane>>4)*8+j; B col=lane&15, same k map; C/D col=lane&15, row=(lane>>4)*4+r.
__device__ __forceinline__ void row_ln(const f32x4 v[8], float mu[4], float rs[4]) {
#pragma unroll
    for (int r = 0; r < 4; ++r) {
        float s = 0.f;
#pragma unroll
        for (int nt = 0; nt < 8; ++nt) s += v[nt][r];
        s += __shfl_xor(s, 1); s += __shfl_xor(s, 2);
        s += __shfl_xor(s, 4); s += __shfl_xor(s, 8);
        float m_ = s * 0.0078125f;
        float q = 0.f;
#pragma unroll
        for (int nt = 0; nt < 8; ++nt) { float d = v[nt][r] - m_; q += d * d; }
        q += __shfl_xor(q, 1); q += __shfl_xor(q, 2);
        q += __shfl_xor(q, 4); q += __shfl_xor(q, 8);
        mu[r] = m_;
        rs[r] = rsqrtf(q * 0.0078125f + 1e-5f);
    }
}

// ============ PATH A: R15 structure, panels staged from wT =================
__global__ __launch_bounds__(512) void enc_stage_wt(
    const float* __restrict__ feat, const float* __restrict__ pos,
    const unsigned char* __restrict__ maskb, const u16* __restrict__ wT,
    const float* __restrict__ bq, const float* __restrict__ bk,
    const float* __restrict__ bv, const float* __restrict__ bo,
    const float* __restrict__ b1, const float* __restrict__ b2,
    const float* __restrict__ g1, const float* __restrict__ be1,
    const float* __restrict__ g2, const float* __restrict__ be2,
    float* __restrict__ out) {
    __shared__ __align__(16) char smem[159744];

    const int tid  = threadIdx.x;
    const int lane = tid & 63;
    const int wid  = tid >> 6;
    const int ww   = wid >> 2;
    const int m0   = (wid & 3) * 16;
    const int lr   = lane & 15;
    const int lk   = lane >> 4;
    const int w    = blockIdx.x * 2 + ww;

    char* wb   = smem + ww * 62464;
    u16* sQ    = (u16*)wb;
    u16* sK    = (u16*)(wb + 17408);
    u16* sVt   = (u16*)(wb + 34816);
    u16* sAttn = (u16*)(wb + 53248);
    u16* sF1   = (u16*)(wb + 17408);
    u16* panA  = (u16*)(smem + 124928);
    u16* panB  = (u16*)(smem + 142336);

    const u16* WQt = wT;
    const u16* WKt = wT + 16384;
    const u16* WVt = wT + 32768;
    const u16* WOt = wT + 49152;
    const u16* W1t = wT + 65536;              // [256][128]
    const u16* W2t = wT + 98304;              // [128][256]

    const float* fw = feat + (size_t)w * 8192;
    const float* pw = pos  + (size_t)w * 8192;

    stage_wt(WQt, 128, 0, 0, panA, tid);

    int vld;
    {
        unsigned char smp = maskb[lane * 64 + 63];
        int ones = __popcll(__ballot(smp != 0));
        int m = (ones > 32) ? (maskb[(size_t)w * 64 + lane] != 0)
                            : (((const int*)maskb)[(size_t)w * 64 + lane] != 0);
        vld = 64 - __popcll(__ballot(m));
    }

    bf16x8 aX[4], aFv[4];
#pragma unroll
    for (int ks = 0; ks < 4; ++ks) {
        const float* fp = fw + (m0 + lr) * 128 + ks * 32 + lk * 8;
        const float* pp = pw + (m0 + lr) * 128 + ks * 32 + lk * 8;
        f32x4 f0 = *(const f32x4*)fp;
        f32x4 f1 = *(const f32x4*)(fp + 4);
        f32x4 p0 = *(const f32x4*)pp;
        f32x4 p1 = *(const f32x4*)(pp + 4);
        aFv[ks] = pack8(f0, f1);
        aX[ks]  = pack8(f0 + p0, f1 + p1);
    }
    __syncthreads();

    {   stage_wt(WQt, 128, 64, 0, panB, tid);
        f32x4 acc[4] = {};
        gemm_h(aX, panA, lr, lk, acc);
#pragma unroll
        for (int nt = 0; nt < 4; ++nt) {
            int col = nt * 16 + lr; float bb = bq[col];
#pragma unroll
            for (int r = 0; r < 4; ++r)
                sQ[(m0 + lk * 4 + r) * 136 + col] = f2bf(acc[nt][r] + bb);
        }
        __syncthreads();
    }
    {   stage_wt(WKt, 128, 0, 0, panA, tid);
        f32x4 acc[4] = {};
        gemm_h(aX, panB, lr, lk, acc);
#pragma unroll
        for (int nt = 0; nt < 4; ++nt) {
            int col = 64 + nt * 16 + lr; float bb = bq[col];
#pragma unroll
            for (int r = 0; r < 4; ++r)
                sQ[(m0 + lk * 4 + r) * 136 + col] = f2bf(acc[nt][r] + bb);
        }
        __syncthreads();
    }
    {   stage_wt(WKt, 128, 64, 0, panB, tid);
        f32x4 acc[4] = {};
        gemm_h(aX, panA, lr, lk, acc);
#pragma unroll
        for (int nt = 0; nt < 4; ++nt) {
            int col = nt * 16 + lr; float bb = bk[col];
#pragma unroll
            for (int r = 0; r < 4; ++r)
                sK[(m0 + lk * 4 + r) * 136 + col] = f2bf(acc[nt][r] + bb);
        }
        __syncthreads();
    }
    {   stage_wt(WVt, 128, 0, 0, panA, tid);
        f32x4 acc[4] = {};
        gemm_h(aX, panB, lr, lk, acc);
#pragma unroll
        for (int nt = 0; nt < 4; ++nt) {
            int col = 64 + nt * 16 + lr; float bb = bk[col];
#pragma unroll
            for (int r = 0; r < 4; ++r)
                sK[(m0 + lk * 4 + r) * 136 + col] = f2bf(acc[nt][r] + bb);
        }
        __syncthreads();
    }
    {   stage_wt(WVt, 128, 64, 0, panB, tid);
        f32x4 acc[4] = {};
        gemm_h(aFv, panA, lr, lk, acc);
#pragma unroll
        for (int nt = 0; nt < 4; ++nt) {
            int dcol = nt * 16 + lr; float bb = bv[dcol];
            float e0 = acc[nt][0] + bb, e1 = acc[nt][1] + bb;
            float e2 = acc[nt][2] + bb, e3 = acc[nt][3] + bb;
            u32 lo, hi;
            asm("v_cvt_pk_bf16_f32 %0, %1, %2" : "=v"(lo) : "v"(e0), "v"(e1));
            asm("v_cvt_pk_bf16_f32 %0, %1, %2" : "=v"(hi) : "v"(e2), "v"(e3));
            uint2 pk; pk.x = lo; pk.y = hi;
            *(uint2*)(sVt + dcol * 72 + m0 + lk * 4) = pk;
        }
        __syncthreads();
    }
    {   stage_wt(WOt, 128, 0, 0, panA, tid);
        f32x4 acc[4] = {};
        gemm_h(aFv, panB, lr, lk, acc);
#pragma unroll
        for (int nt = 0; nt < 4; ++nt) {
            int dcol = 64 + nt * 16 + lr; float bb = bv[dcol];
            float e0 = acc[nt][0] + bb, e1 = acc[nt][1] + bb;
            float e2 = acc[nt][2] + bb, e3 = acc[nt][3] + bb;
            u32 lo, hi;
            asm("v_cvt_pk_bf16_f32 %0, %1, %2" : "=v"(lo) : "v"(e0), "v"(e1));
            asm("v_cvt_pk_bf16_f32 %0, %1, %2" : "=v"(hi) : "v"(e2), "v"(e3));
            uint2 pk; pk.x = lo; pk.y = hi;
            *(uint2*)(sVt + dcol * 72 + m0 + lk * 4) = pk;
        }
        __syncthreads();
    }

    stage_wt(WOt, 128, 64, 0, panB, tid);
    const int dup = (lk & 1) * 8;
#pragma unroll 1
    for (int h = 0; h < 8; ++h) {
        bf16x8 aQ = *(const bf16x8*)(sQ + (m0 + lr) * 136 + h * 16 + dup);
        f32x4 sc[4];
#pragma unroll
        for (int nt = 0; nt < 4; ++nt) {
            bf16x8 bK = *(const bf16x8*)(sK + (nt * 16 + lr) * 136 + h * 16 + dup);
            f32x4 zz = {0.f, 0.f, 0.f, 0.f};
            sc[nt] = MFMA16(aQ, bK, zz);
        }
#pragma unroll
        for (int nt = 0; nt < 4; ++nt) {
            bool msk = (nt * 16 + lr) >= vld;
#pragma unroll
            for (int r = 0; r < 4; ++r) {
                float v0 = sc[nt][r] * 0.125f;
                sc[nt][r] = msk ? -1e9f : v0;
            }
        }
        float mx[4], sm[4];
#pragma unroll
        for (int r = 0; r < 4; ++r) {
            float m_ = fmaxf(fmaxf(sc[0][r], sc[1][r]), fmaxf(sc[2][r], sc[3][r]));
            m_ = fmaxf(m_, __shfl_xor(m_, 1));
            m_ = fmaxf(m_, __shfl_xor(m_, 2));
            m_ = fmaxf(m_, __shfl_xor(m_, 4));
            m_ = fmaxf(m_, __shfl_xor(m_, 8));
            mx[r] = m_; sm[r] = 0.f;
        }
#pragma unroll
        for (int nt = 0; nt < 4; ++nt)
#pragma unroll
            for (int r = 0; r < 4; ++r) {
                float e = __expf(sc[nt][r] - mx[r]);
                sc[nt][r] = e; sm[r] += e;
            }
#pragma unroll
        for (int r = 0; r < 4; ++r) {
            float s_ = sm[r];
            s_ += __shfl_xor(s_, 1); s_ += __shfl_xor(s_, 2);
            s_ += __shfl_xor(s_, 4); s_ += __shfl_xor(s_, 8);
            sm[r] = 1.f / s_;
        }
#pragma unroll
        for (int nt = 0; nt < 4; ++nt)
#pragma unroll
            for (int r = 0; r < 4; ++r)
                sAttn[(m0 + lk * 4 + r) * 72 + nt * 16 + lr] = f2bf(sc[nt][r] * sm[r]);
        CFENCE();
        f32x4 cc = {0.f, 0.f, 0.f, 0.f};
#pragma unroll
        for (int ks = 0; ks < 2; ++ks) {
            bf16x8 aP = *(const bf16x8*)(sAttn + (m0 + lr) * 72 + ks * 32 + lk * 8);
            bf16x8 bV = *(const bf16x8*)(sVt + (h * 16 + lr) * 72 + ks * 32 + lk * 8);
            cc = MFMA16(aP, bV, cc);
        }
#pragma unroll
        for (int r = 0; r < 4; ++r)
            sQ[(m0 + lk * 4 + r) * 136 + h * 16 + lr] = f2bf(cc[r]);
    }
    CFENCE();
    __syncthreads();

    bf16x8 aC[4];
#pragma unroll
    for (int ks = 0; ks < 4; ++ks)
        aC[ks] = *(const bf16x8*)(sQ + (m0 + lr) * 136 + ks * 32 + lk * 8);
    f32x4 v8[8];
    {   f32x4 acc[4] = {};
        gemm_h(aC, panA, lr, lk, acc);
#pragma unroll
        for (int nt = 0; nt < 4; ++nt) {
            int col = nt * 16 + lr; float bb = bo[col];
#pragma unroll
            for (int r = 0; r < 4; ++r)
                v8[nt][r] = acc[nt][r] + bb + fw[(m0 + lk * 4 + r) * 128 + col];
        }
        __syncthreads();
    }
    {   stage_wt(W1t, 128, 0, 0, panA, tid);
        f32x4 acc[4] = {};
        gemm_h(aC, panB, lr, lk, acc);
#pragma unroll
        for (int nt = 0; nt < 4; ++nt) {
            int col = 64 + nt * 16 + lr; float bb = bo[col];
#pragma unroll
            for (int r = 0; r < 4; ++r)
                v8[4 + nt][r] = acc[nt][r] + bb + fw[(m0 + lk * 4 + r) * 128 + col];
        }
        __syncthreads();
    }
    float mu[4], rs[4];
    row_ln(v8, mu, rs);
    f32x4 srcv[8];
#pragma unroll
    for (int nt = 0; nt < 8; ++nt) {
        int col = nt * 16 + lr;
        float gg = g1[col], bb = be1[col];
#pragma unroll
        for (int r = 0; r < 4; ++r) {
            float sv = (v8[nt][r] - mu[r]) * rs[r] * gg + bb;
            srcv[nt][r] = sv;
            sQ[(m0 + lk * 4 + r) * 136 + col] = f2bf(sv);
        }
    }
    CFENCE();
    bf16x8 aS[4];
#pragma unroll
    for (int ks = 0; ks < 4; ++ks)
        aS[ks] = *(const bf16x8*)(sQ + (m0 + lr) * 136 + ks * 32 + lk * 8);

#pragma unroll
    for (int hf = 0; hf < 4; ++hf) {
        u16* cur = (hf & 1) ? panB : panA;
        u16* nxt = (hf & 1) ? panA : panB;
        if (hf < 3) stage_wt(W1t, 128, (hf + 1) * 64, 0, nxt, tid);
        else        stage_wt(W2t, 256, 0, 0, nxt, tid);
        f32x4 f1a[4] = {};
        gemm_h(aS, cur, lr, lk, f1a);
#pragma unroll
        for (int nt = 0; nt < 4; ++nt) {
            int col = hf * 64 + nt * 16 + lr; float bb = b1[col];
#pragma unroll
            for (int r = 0; r < 4; ++r)
                sF1[(m0 + lk * 4 + r) * 264 + col] = f2bf(fmaxf(f1a[nt][r] + bb, 0.f));
        }
        __syncthreads();
    }

    f32x4 oa[8] = {};
#pragma unroll
    for (int s = 0; s < 4; ++s) {
        u16* cur = (s & 1) ? panB : panA;
        u16* nxt = (s & 1) ? panA : panB;
        if (s < 3) {
            int ns = s + 1, nkh = ns >> 1, nnh = ns & 1;
            stage_wt(W2t, 256, nnh * 64, nkh * 128, nxt, tid);
        }
        int kh = s >> 1, nh = s & 1;
#pragma unroll
        for (int ks = 0; ks < 4; ++ks) {
            bf16x8 aF = *(const bf16x8*)(sF1 + (m0 + lr) * 264 + kh * 128 + ks * 32 + lk * 8);
#pragma unroll
            for (int nt = 0; nt < 4; ++nt) {
                bf16x8 b = *(const bf16x8*)(cur + (nt * 16 + lr) * 136 + ks * 32 + lk * 8);
                oa[nh * 4 + nt] = MFMA16(aF, b, oa[nh * 4 + nt]);
            }
        }
        if (s < 3) __syncthreads();
    }

#pragma unroll
    for (int nt = 0; nt < 8; ++nt) {
        int col = nt * 16 + lr; float bb = b2[col];
#pragma unroll
        for (int r = 0; r < 4; ++r)
            v8[nt][r] = oa[nt][r] + bb + srcv[nt][r];
    }
    row_ln(v8, mu, rs);
    float* ow = out + (size_t)w * 8192;
#pragma unroll
    for (int nt = 0; nt < 8; ++nt) {
        int col = nt * 16 + lr;
        float gg = g2[col], bb = be2[col];
#pragma unroll
        for (int r = 0; r < 4; ++r)
            ow[(m0 + lk * 4 + r) * 128 + col] = (v8[nt][r] - mu[r]) * rs[r] * gg + bb;
    }
}

// ============ PATH B: R15 fallback, verbatim (proven 337 us) ===============
__global__ __launch_bounds__(512) void enc_fallback(
    const float* __restrict__ feat, const float* __restrict__ pos,
    const unsigned char* __restrict__ maskb,
    const float* __restrict__ Wq, const float* __restrict__ bq,
    const float* __restrict__ Wk, const float* __restrict__ bk,
    const float* __restrict__ Wv, const float* __restrict__ bv,
    const float* __restrict__ Wo, const float* __restrict__ bo,
    const float* __restrict__ W1, const float* __restrict__ b1,
    const float* __restrict__ W2, const float* __restrict__ b2,
    const float* __restrict__ g1, const float* __restrict__ be1,
    const float* __restrict__ g2, const float* __restrict__ be2,
    float* __restrict__ out) {
    __shared__ __align__(16) char smem[159744];

    const int tid  = threadIdx.x;
    const int lane = tid & 63;
    const int wid  = tid >> 6;
    const int ww   = wid >> 2;
    const int m0   = (wid & 3) * 16;
    const int lr   = lane & 15;
    const int lk   = lane >> 4;
    const int w    = blockIdx.x * 2 + ww;

    char* wb   = smem + ww * 62464;
    u16* sQ    = (u16*)wb;
    u16* sK    = (u16*)(wb + 17408);
    u16* sVt   = (u16*)(wb + 34816);
    u16* sAttn = (u16*)(wb + 53248);
    u16* sF1   = (u16*)(wb + 17408);
    u16* panA  = (u16*)(smem + 124928);
    u16* panB  = (u16*)(smem + 142336);

    const float* fw = feat + (size_t)w * 8192;
    const float* pw = pos  + (size_t)w * 8192;

    stage_h(Wq, 128, 0, 0, panA, tid);

    int vld;
    {
        unsigned char smp = maskb[lane * 64 + 63];
        int ones = __popcll(__ballot(smp != 0));
        int m = (ones > 32) ? (maskb[(size_t)w * 64 + lane] != 0)
                            : (((const int*)maskb)[(size_t)w * 64 + lane] != 0);
        vld = 64 - __popcll(__ballot(m));
    }

    bf16x8 aX[4], aFv[4];
#pragma unroll
    for (int ks = 0; ks < 4; ++ks) {
        const float* fp = fw + (m0 + lr) * 128 + ks * 32 + lk * 8;
        const float* pp = pw + (m0 + lr) * 128 + ks * 32 + lk * 8;
        f32x4 f0 = *(const f32x4*)fp;
        f32x4 f1 = *(const f32x4*)(fp + 4);
        f32x4 p0 = *(const f32x4*)pp;
        f32x4 p1 = *(const f32x4*)(pp + 4);
        aFv[ks] = pack8(f0, f1);
        aX[ks]  = pack8(f0 + p0, f1 + p1);
    }
    __syncthreads();

    {   stage_h(Wq, 128, 64, 0, panB, tid);
        f32x4 acc[4] = {};
        gemm_h(aX, panA, lr, lk, acc);
#pragma unroll
        for (int nt = 0; nt < 4; ++nt) {
            int col = nt * 16 + lr; float bb = bq[col];
#pragma unroll
            for (int r = 0; r < 4; ++r)
                sQ[(m0 + lk * 4 + r) * 136 + col] = f2bf(acc[nt][r] + bb);
        }
        __syncthreads();
    }
    {   stage_h(Wk, 128, 0, 0, panA, tid);
        f32x4 acc[4] = {};
        gemm_h(aX, panB, lr, lk, acc);
#pragma unroll
        for (int nt = 0; nt < 4; ++nt) {
            int col = 64 + nt * 16 + lr; float bb = bq[col];
#pragma unroll
            for (int r = 0; r < 4; ++r)
                sQ[(m0 + lk * 4 + r) * 136 + col] = f2bf(acc[nt][r] + bb);
        }
        __syncthreads();
    }
    {   stage_h(Wk, 128, 64, 0, panB, tid);
        f32x4 acc[4] = {};
        gemm_h(aX, panA, lr, lk, acc);
#pragma unroll
        for (int nt = 0; nt < 4; ++nt) {
            int col = nt * 16 + lr; float bb = bk[col];
#pragma unroll
            for (int r = 0; r < 4; ++r)
                sK[(m0 + lk * 4 + r) * 136 + col] = f2bf(acc[nt][r] + bb);
        }
        __syncthreads();
    }
    {   stage_h(Wv, 128, 0, 0, panA, tid);
        f32x4 acc[4] = {};
        gemm_h(aX, panB, lr, lk, acc);
#pragma unroll
        for (int nt = 0; nt < 4; ++nt) {
            int col = 64 + nt * 16 + lr; float bb = bk[col];
#pragma unroll
            for (int r = 0; r < 4; ++r)
                sK[(m0 + lk * 4 + r) * 136 + col] = f2bf(acc[nt][r] + bb);
        }
        __syncthreads();
    }
    {   stage_h(Wv, 128, 64, 0, panB, tid);
        f32x4 acc[4] = {};
        gemm_h(aFv, panA, lr, lk, acc);
#pragma unroll
        for (int nt = 0; nt < 4; ++nt) {
            int dcol = nt * 16 + lr; float bb = bv[dcol];
            float e0 = acc[nt][0] + bb, e1 = acc[nt][1] + bb;
            float e2 = acc[nt][2] + bb, e3 = acc[nt][3] + bb;
            u32 lo, hi;
            asm("v_cvt_pk_bf16_f32 %0, %1, %2" : "=v"(lo) : "v"(e0), "v"(e1));
            asm("v_cvt_pk_bf16_f32 %0, %1, %2" : "=v"(hi) : "v"(e2), "v"(e3));
            uint2 pk; pk.x = lo; pk.y = hi;
            *(uint2*)(sVt + dcol * 72 + m0 + lk * 4) = pk;
        }
        __syncthreads();
    }
    {   stage_h(Wo, 128, 0, 0, panA, tid);
        f32x4 acc[4] = {};
        gemm_h(aFv, panB, lr, lk, acc);
#pragma unroll
        for (int nt = 0; nt < 4; ++nt) {
            int dcol = 64 + nt * 16 + lr; float bb = bv[dcol];
            float e0 = acc[nt][0] + bb, e1 = acc[nt][1] + bb;
            float e2 = acc[nt][2] + bb, e3 = acc[nt][3] + bb;
            u32 lo, hi;
            asm("v_cvt_pk_bf16_f32 %0, %1, %2" : "=v"(lo) : "v"(e0), "v"(e1));
            asm("v_cvt_pk_bf16_f32 %0, %1, %2" : "=v"(hi) : "v"(e2), "v"(e3));
            uint2 pk; pk.x = lo; pk.y = hi;
            *(uint2*)(sVt + dcol * 72 + m0 + lk * 4) = pk;
        }
        __syncthreads();
    }

    stage_h(Wo, 128, 64, 0, panB, tid);
    const int dup = (lk & 1) * 8;
#pragma unroll 1
    for (int h = 0; h < 8; ++h) {
        bf16x8 aQ = *(const bf16x8*)(sQ + (m0 + lr) * 136 + h * 16 + dup);
        f32x4 sc[4];
#pragma unroll
        for (int nt = 0; nt < 4; ++nt) {
            bf16x8 bK = *(const bf16x8*)(sK + (nt * 16 + lr) * 136 + h * 16 + dup);
            f32x4 zz = {0.f, 0.f, 0.f, 0.f};
            sc[nt] = MFMA16(aQ, bK, zz);
        }
#pragma unroll
        for (int nt = 0; nt < 4; ++nt) {
            bool msk = (nt * 16 + lr) >= vld;
#pragma unroll
            for (int r = 0; r < 4; ++r) {
                float v0 = sc[nt][r] * 0.125f;
                sc[nt][r] = msk ? -1e9f : v0;
            }
        }
        float mx[4], sm[4];
#pragma unroll
        for (int r = 0; r < 4; ++r) {
            float m_ = fmaxf(fmaxf(sc[0][r], sc[1][r]), fmaxf(sc[2][r], sc[3][r]));
            m_ = fmaxf(m_, __shfl_xor(m_, 1));
            m_ = fmaxf(m_, __shfl_xor(m_, 2));
            m_ = fmaxf(m_, __shfl_xor(m_, 4));
            m_ = fmaxf(m_, __shfl_xor(m_, 8));
            mx[r] = m_; sm[r] = 0.f;
        }
#pragma unroll
        for (int nt = 0; nt < 4; ++nt)
#pragma unroll
            for (int r = 0; r < 4; ++r) {
                float e = __expf(sc[nt][r] - mx[r]);
                sc[nt][r] = e; sm[r] += e;
            }
#pragma unroll
        for (int r = 0; r < 4; ++r) {
            float s_ = sm[r];
            s_ += __shfl_xor(s_, 1); s_ += __shfl_xor(s_, 2);
            s_ += __shfl_xor(s_, 4); s_ += __shfl_xor(s_, 8);
            sm[r] = 1.f / s_;
        }
#pragma unroll
        for (int nt = 0; nt < 4; ++nt)
#pragma unroll
            for (int r = 0; r < 4; ++r)
                sAttn[(m0 + lk * 4 + r) * 72 + nt * 16 + lr] = f2bf(sc[nt][r] * sm[r]);
        CFENCE();
        f32x4 cc = {0.f, 0.f, 0.f, 0.f};
#pragma unroll
        for (int ks = 0; ks < 2; ++ks) {
            bf16x8 aP = *(const bf16x8*)(sAttn + (m0 + lr) * 72 + ks * 32 + lk * 8);
            bf16x8 bV = *(const bf16x8*)(sVt + (h * 16 + lr) * 72 + ks * 32 + lk * 8);
            cc = MFMA16(aP, bV, cc);
        }
#pragma unroll
        for (int r = 0; r < 4; ++r)
            sQ[(m0 + lk * 4 + r) * 136 + h * 16 + lr] = f2bf(cc[r]);
    }
    CFENCE();
    __syncthreads();

    bf16x8 aC[4];
#pragma unroll
    for (int ks = 0; ks < 4; ++ks)
        aC[ks] = *(const bf16x8*)(sQ + (m0 + lr) * 136 + ks * 32 + lk * 8);
    f32x4 v8[8];
    {   f32x4 acc[4] = {};
        gemm_h(aC, panA, lr, lk, acc);
#pragma unroll
        for (int nt = 0; nt < 4; ++nt) {
            int col = nt * 16 + lr; float bb = bo[col];
#pragma unroll
            for (int r = 0; r < 4; ++r)
                v8[nt][r] = acc[nt][r] + bb + fw[(m0 + lk * 4 + r) * 128 + col];
        }
        __syncthreads();
    }
    {   stage_h(W1, 256, 0, 0, panA, tid);
        f32x4 acc[4] = {};
        gemm_h(aC, panB, lr, lk, acc);
#pragma unroll
        for (int nt = 0; nt < 4; ++nt) {
            int col = 64 + nt * 16 + lr; float bb = bo[col];
#pragma unroll
            for (int r = 0; r < 4; ++r)
                v8[4 + nt][r] = acc[nt][r] + bb + fw[(m0 + lk * 4 + r) * 128 + col];
        }
        __syncthreads();
    }
    float mu[4], rs[4];
    row_ln(v8, mu, rs);
    f32x4 srcv[8];
#pragma unroll
    for (int nt = 0; nt < 8; ++nt) {
        int col = nt * 16 + lr;
        float gg = g1[col], bb = be1[col];
#pragma unroll
        for (int r = 0; r < 4; ++r) {
            float sv = (v8[nt][r] - mu[r]) * rs[r] * gg + bb;
            srcv[nt][r] = sv;
            sQ[(m0 + lk * 4 + r) * 136 + col] = f2bf(sv);
        }
    }
    CFENCE();
    bf16x8 aS[4];
#pragma unroll
    for (int ks = 0; ks < 4; ++ks)
        aS[ks] = *(const bf16x8*)(sQ + (m0 + lr) * 136 + ks * 32 + lk * 8);

#pragma unroll
    for (int hf = 0; hf < 4; ++hf) {
        u16* cur = (hf & 1) ? panB : panA;
        u16* nxt = (hf & 1) ? panA : panB;
        if (hf < 3) stage_h(W1, 256, (hf + 1) * 64, 0, nxt, tid);
        else        stage_h(W2, 128, 0, 0, nxt, tid);
        f32x4 f1a[4] = {};
        gemm_h(aS, cur, lr, lk, f1a);
#pragma unroll
        for (int nt = 0; nt < 4; ++nt) {
            int col = hf * 64 + nt * 16 + lr; float bb = b1[col];
#pragma unroll
            for (int r = 0; r < 4; ++r)
                sF1[(m0 + lk * 4 + r) * 264 + col] = f2bf(fmaxf(f1a[nt][r] + bb, 0.f));
        }
        __syncthreads();
    }

    f32x4 oa[8] = {};
#pragma unroll
    for (int s = 0; s < 4; ++s) {
        u16* cur = (s & 1) ? panB : panA;
        u16* nxt = (s & 1) ? panA : panB;
        if (s < 3) {
            int ns = s + 1, nkh = ns >> 1, nnh = ns & 1;
            stage_h(W2, 128, nnh * 64, nkh * 128, nxt, tid);
        }
        int kh = s >> 1, nh = s & 1;
#pragma unroll
        for (int ks = 0; ks < 4; ++ks) {
            bf16x8 aF = *(const bf16x8*)(sF1 + (m0 + lr) * 264 + kh * 128 + ks * 32 + lk * 8);
#pragma unroll
            for (int nt = 0; nt < 4; ++nt) {
                bf16x8 b = *(const bf16x8*)(cur + (nt * 16 + lr) * 136 + ks * 32 + lk * 8);
                oa[nh * 4 + nt] = MFMA16(aF, b, oa[nh * 4 + nt]);
            }
        }
        if (s < 3) __syncthreads();
    }

#pragma unroll
    for (int nt = 0; nt < 8; ++nt) {
        int col = nt * 16 + lr; float bb = b2[col];
#pragma unroll
        for (int r = 0; r < 4; ++r)
            v8[nt][r] = oa[nt][r] + bb + srcv[nt][r];
    }
    row_ln(v8, mu, rs);
    float* ow = out + (size_t)w * 8192;
#pragma unroll
    for (int nt = 0; nt < 8; ++nt) {
        int col = nt * 16 + lr;
        float gg = g2[col], bb = be2[col];
#pragma unroll
        for (int r = 0; r < 4; ++r)
            ow[(m0 + lk * 4 + r) * 128 + col] = (v8[nt][r] - mu[r]) * rs[r] * gg + bb;
    }
}

extern "C" void kernel_launch(void* const* d_in, const int* in_sizes, int n_in,
                              void* d_out, int out_size, void* d_ws, size_t ws_size,
                              hipStream_t stream) {
    (void)in_sizes; (void)n_in; (void)out_size;
    const float* feat = (const float*)d_in[0];
    const float* pos  = (const float*)d_in[1];
    const unsigned char* mask = (const unsigned char*)d_in[2];
    const float* Wq = (const float*)d_in[3];  const float* bq = (const float*)d_in[4];
    const float* Wk = (const float*)d_in[5];  const float* bk = (const float*)d_in[6];
    const float* Wv = (const float*)d_in[7];  const float* bv = (const float*)d_in[8];
    const float* Wo = (const float*)d_in[9];  const float* bo = (const float*)d_in[10];
    const float* W1 = (const float*)d_in[11]; const float* b1 = (const float*)d_in[12];
    const float* W2 = (const float*)d_in[13]; const float* b2 = (const float*)d_in[14];
    const float* g1 = (const float*)d_in[15]; const float* be1 = (const float*)d_in[16];
    const float* g2 = (const float*)d_in[17]; const float* be2 = (const float*)d_in[18];

    if (ws_size >= 262144) {
        u16* wT = (u16*)d_ws;
        conv_w_k<<<512, 256, 0, stream>>>(Wq, Wk, Wv, Wo, W1, W2, wT);
        enc_stage_wt<<<2048, 512, 0, stream>>>(feat, pos, mask, wT,
                                               bq, bk, bv, bo, b1, b2,
                                               g1, be1, g2, be2, (float*)d_out);
    } else {
        enc_fallback<<<2048, 512, 0, stream>>>(feat, pos, mask,
                                               Wq, bq, Wk, bk, Wv, bv, Wo, bo,
                                               W1, b1, W2, b2, g1, be1, g2, be2,
                                               (float*)d_out);
    }
}

// Round 20
// 331.609 us; speedup vs baseline: 1.0217x; 1.0217x over previous
//
#include <hip/hip_runtime.h>

typedef __attribute__((ext_vector_type(8))) short bf16x8;
typedef __attribute__((ext_vector_type(4))) float f32x4;
typedef unsigned short u16;
typedef unsigned int u32;

#define MFMA16(a, b, c) __builtin_amdgcn_mfma_f32_16x16x32_bf16((a), (b), (c), 0, 0, 0)
#define CFENCE() asm volatile("" ::: "memory")

// FINAL (R20) = R15 verbatim: the most-validated fast configuration.
// 512 threads = 8 waves; waves 0-3 -> window 2*bid, waves 4-7 -> 2*bid+1.
// Per-window LDS (62464 B) + double-buffered shared weight panels
// (2 x 17408 B) = 159744 B -> 1 block/CU. Single kernel, NO d_ws.
// WHY THIS CONFIG (session evidence):
//  - d_ws/conv_w_k family: first-call failures R1-R4/R16A and graph-replay
//    nondeterminism R19 -> banned.
//  - 2 blocks/CU: failed 3/3 (R8/R9/R10; R11 bisect) -> banned.
//  - multi-delta micro-opt bundles: broke 3/3 (R8/R14/R18) -> frozen.
//  - this exact source: passed bench + graph replay + rocprof at 337 us.
// INVARIANTS: LDS row strides on bf16x8 paths x8 u16 (136/72/264); panel
// chain Q0:A Q1:B K0:A K1:B V0:A V1:B attn|Wo1->B O0:A O1:B|W1_0->A
// F0:A F1:B F2:A F3:B|W2_00->A S0:A S1:B S2:A S3:B (stage targets the
// buffer consumed 2 steps earlier; every cross-wave RAW/WAR crosses a barrier).

__device__ __forceinline__ u16 f2bf(float f) {
    union { float f; u32 u; } c; c.f = f;
    u32 r = c.u + 0x7fffu + ((c.u >> 16) & 1u);   // RNE
    return (u16)(r >> 16);
}

__device__ __forceinline__ bf16x8 pack8(f32x4 a, f32x4 b) {
    union { u32 w[4]; bf16x8 v; } r;
    asm("v_cvt_pk_bf16_f32 %0, %1, %2" : "=v"(r.w[0]) : "v"(a[0]), "v"(a[1]));
    asm("v_cvt_pk_bf16_f32 %0, %1, %2" : "=v"(r.w[1]) : "v"(a[2]), "v"(a[3]));
    asm("v_cvt_pk_bf16_f32 %0, %1, %2" : "=v"(r.w[2]) : "v"(b[0]), "v"(b[1]));
    asm("v_cvt_pk_bf16_f32 %0, %1, %2" : "=v"(r.w[3]) : "v"(b[2]), "v"(b[3]));
    return r.v;
}

// stage a [64 n][128 k] transposed bf16 half-panel, row stride 136:
// sW[n][k] = W[k0+k][n0+n]. 2048 quads / 512 thr = 4 per thread.
__device__ __forceinline__ void stage_h(const float* __restrict__ W, int ld,
                                        int n0, int k0, u16* __restrict__ sW,
                                        int t) {
#pragma unroll
    for (int i = 0; i < 4; ++i) {
        int e = i * 512 + t;                      // 0..2047
        int n = e & 63, kq = e >> 6;              // n 0..63, kq 0..31
        const float* src = W + (size_t)(k0 + kq * 4) * ld + n0 + n;
        float a = src[0], b = src[ld], c = src[2 * ld], d = src[3 * ld];
        u32 lo, hi;
        asm("v_cvt_pk_bf16_f32 %0, %1, %2" : "=v"(lo) : "v"(a), "v"(b));
        asm("v_cvt_pk_bf16_f32 %0, %1, %2" : "=v"(hi) : "v"(c), "v"(d));
        uint2 pk; pk.x = lo; pk.y = hi;
        *(uint2*)(sW + n * 136 + kq * 4) = pk;    // 8B-aligned
    }
}

// half of a GEMM: 4 col-tiles x 4 k-steps = 16 MFMA against the staged panel
__device__ __forceinline__ void gemm_h(const bf16x8 aF[4], const u16* __restrict__ sW,
                                       int lr, int lk, f32x4 acc[4]) {
#pragma unroll
    for (int ks = 0; ks < 4; ++ks)
#pragma unroll
        for (int nt = 0; nt < 4; ++nt) {
            bf16x8 b = *(const bf16x8*)(sW + (nt * 16 + lr) * 136 + ks * 32 + lk * 8);
            acc[nt] = MFMA16(aF[ks], b, acc[nt]);
        }
}

// MFMA 16x16x32 bf16 (pinned: learn_hip m89/m91/m97): A row=lane&15,
// k=(lane>>4)*8+j; B col=lane&15, same k map; C/D col=lane&15, row=(lane>>4)*4+r.
__device__ __forceinline__ void row_ln(const f32x4 v[8], float mu[4], float rs[4]) {
#pragma unroll
    for (int r = 0; r < 4; ++r) {
        float s = 0.f;
#pragma unroll
        for (int nt = 0; nt < 8; ++nt) s += v[nt][r];
        s += __shfl_xor(s, 1); s += __shfl_xor(s, 2);
        s += __shfl_xor(s, 4); s += __shfl_xor(s, 8);
        float m_ = s * 0.0078125f;
        float q = 0.f;
#pragma unroll
        for (int nt = 0; nt < 8; ++nt) { float d = v[nt][r] - m_; q += d * d; }
        q += __shfl_xor(q, 1); q += __shfl_xor(q, 2);
        q += __shfl_xor(q, 4); q += __shfl_xor(q, 8);
        mu[r] = m_;
        rs[r] = rsqrtf(q * 0.0078125f + 1e-5f);
    }
}

__global__ __launch_bounds__(512) void enc_main(
    const float* __restrict__ feat, const float* __restrict__ pos,
    const unsigned char* __restrict__ maskb,
    const float* __restrict__ Wq, const float* __restrict__ bq,
    const float* __restrict__ Wk, const float* __restrict__ bk,
    const float* __restrict__ Wv, const float* __restrict__ bv,
    const float* __restrict__ Wo, const float* __restrict__ bo,
    const float* __restrict__ W1, const float* __restrict__ b1,
    const float* __restrict__ W2, const float* __restrict__ b2,
    const float* __restrict__ g1, const float* __restrict__ be1,
    const float* __restrict__ g2, const float* __restrict__ be2,
    float* __restrict__ out) {
    // 2 windows x 62464 + 2 panels x 17408 = 159744 B -> 1 block/CU
    __shared__ __align__(16) char smem[159744];

    const int tid  = threadIdx.x;            // 0..511
    const int lane = tid & 63;
    const int wid  = tid >> 6;                // wave 0..7
    const int ww   = wid >> 2;                // window index within block
    const int m0   = (wid & 3) * 16;          // wave's row base in its window
    const int lr   = lane & 15;
    const int lk   = lane >> 4;
    const int w    = blockIdx.x * 2 + ww;

    char* wb   = smem + ww * 62464;
    u16* sQ    = (u16*)wb;                    // [64][136]  Q -> ctx -> src
    u16* sK    = (u16*)(wb + 17408);          // [64][136]
    u16* sVt   = (u16*)(wb + 34816);          // [128][72]  V^T [d][seq]
    u16* sAttn = (u16*)(wb + 53248);          // [64][72]
    u16* sF1   = (u16*)(wb + 17408);          // [64][264]  overlays sK+sVt
    u16* panA  = (u16*)(smem + 124928);       // [64][136]  shared panel A
    u16* panB  = (u16*)(smem + 142336);       // [64][136]  shared panel B

    const float* fw = feat + (size_t)w * 8192;
    const float* pw = pos  + (size_t)w * 8192;

    // P0 = Wq half0 -> A (hides under mask decode + A-frag loads)
    stage_h(Wq, 128, 0, 0, panA, tid);

    // ---- mask decode, per wave for its window (probe validated R5/R6) ------
    int vld;
    {
        unsigned char smp = maskb[lane * 64 + 63];
        int ones = __popcll(__ballot(smp != 0));
        int m = (ones > 32) ? (maskb[(size_t)w * 64 + lane] != 0)
                            : (((const int*)maskb)[(size_t)w * 64 + lane] != 0);
        vld = 64 - __popcll(__ballot(m));
    }

    // ---- A fragments from global: X = feat+pos, Fv = feat ------------------
    bf16x8 aX[4], aFv[4];
#pragma unroll
    for (int ks = 0; ks < 4; ++ks) {
        const float* fp = fw + (m0 + lr) * 128 + ks * 32 + lk * 8;
        const float* pp = pw + (m0 + lr) * 128 + ks * 32 + lk * 8;
        f32x4 f0 = *(const f32x4*)fp;
        f32x4 f1 = *(const f32x4*)(fp + 4);
        f32x4 p0 = *(const f32x4*)pp;
        f32x4 p1 = *(const f32x4*)(pp + 4);
        aFv[ks] = pack8(f0, f1);
        aX[ks]  = pack8(f0 + p0, f1 + p1);
    }
    __syncthreads();                              // P0 ready

    // ---- Q (2 halves) : consume Pi, stage Pi+1 into other buffer -----------
    {   // Q0: gemm(A)=Wq0, stage Wq1->B
        stage_h(Wq, 128, 64, 0, panB, tid);
        f32x4 acc[4] = {};
        gemm_h(aX, panA, lr, lk, acc);
#pragma unroll
        for (int nt = 0; nt < 4; ++nt) {
            int col = nt * 16 + lr; float bb = bq[col];
#pragma unroll
            for (int r = 0; r < 4; ++r)
                sQ[(m0 + lk * 4 + r) * 136 + col] = f2bf(acc[nt][r] + bb);
        }
        __syncthreads();
    }
    {   // Q1: gemm(B)=Wq1, stage Wk0->A
        stage_h(Wk, 128, 0, 0, panA, tid);
        f32x4 acc[4] = {};
        gemm_h(aX, panB, lr, lk, acc);
#pragma unroll
        for (int nt = 0; nt < 4; ++nt) {
            int col = 64 + nt * 16 + lr; float bb = bq[col];
#pragma unroll
            for (int r = 0; r < 4; ++r)
                sQ[(m0 + lk * 4 + r) * 136 + col] = f2bf(acc[nt][r] + bb);
        }
        __syncthreads();
    }
    {   // K0: gemm(A)=Wk0, stage Wk1->B
        stage_h(Wk, 128, 64, 0, panB, tid);
        f32x4 acc[4] = {};
        gemm_h(aX, panA, lr, lk, acc);
#pragma unroll
        for (int nt = 0; nt < 4; ++nt) {
            int col = nt * 16 + lr; float bb = bk[col];
#pragma unroll
            for (int r = 0; r < 4; ++r)
                sK[(m0 + lk * 4 + r) * 136 + col] = f2bf(acc[nt][r] + bb);
        }
        __syncthreads();
    }
    {   // K1: gemm(B)=Wk1, stage Wv0->A
        stage_h(Wv, 128, 0, 0, panA, tid);
        f32x4 acc[4] = {};
        gemm_h(aX, panB, lr, lk, acc);
#pragma unroll
        for (int nt = 0; nt < 4; ++nt) {
            int col = 64 + nt * 16 + lr; float bb = bk[col];
#pragma unroll
            for (int r = 0; r < 4; ++r)
                sK[(m0 + lk * 4 + r) * 136 + col] = f2bf(acc[nt][r] + bb);
        }
        __syncthreads();
    }
    {   // V0: gemm(A)=Wv0, stage Wv1->B
        stage_h(Wv, 128, 64, 0, panB, tid);
        f32x4 acc[4] = {};
        gemm_h(aFv, panA, lr, lk, acc);
#pragma unroll
        for (int nt = 0; nt < 4; ++nt) {
            int dcol = nt * 16 + lr; float bb = bv[dcol];
            float e0 = acc[nt][0] + bb, e1 = acc[nt][1] + bb;
            float e2 = acc[nt][2] + bb, e3 = acc[nt][3] + bb;
            u32 lo, hi;
            asm("v_cvt_pk_bf16_f32 %0, %1, %2" : "=v"(lo) : "v"(e0), "v"(e1));
            asm("v_cvt_pk_bf16_f32 %0, %1, %2" : "=v"(hi) : "v"(e2), "v"(e3));
            uint2 pk; pk.x = lo; pk.y = hi;
            *(uint2*)(sVt + dcol * 72 + m0 + lk * 4) = pk;
        }
        __syncthreads();
    }
    {   // V1: gemm(B)=Wv1, stage Wo0->A
        stage_h(Wo, 128, 0, 0, panA, tid);
        f32x4 acc[4] = {};
        gemm_h(aFv, panB, lr, lk, acc);
#pragma unroll
        for (int nt = 0; nt < 4; ++nt) {
            int dcol = 64 + nt * 16 + lr; float bb = bv[dcol];
            float e0 = acc[nt][0] + bb, e1 = acc[nt][1] + bb;
            float e2 = acc[nt][2] + bb, e3 = acc[nt][3] + bb;
            u32 lo, hi;
            asm("v_cvt_pk_bf16_f32 %0, %1, %2" : "=v"(lo) : "v"(e0), "v"(e1));
            asm("v_cvt_pk_bf16_f32 %0, %1, %2" : "=v"(hi) : "v"(e2), "v"(e3));
            uint2 pk; pk.x = lo; pk.y = hi;
            *(uint2*)(sVt + dcol * 72 + m0 + lk * 4) = pk;
        }
        __syncthreads();   // K, Vt visible; Wo0(A) staged
    }

    // ---- MFMA attention (wave-local; stage Wo1->B under it) ----------------
    // dup trick: both 16-wide K-halves carry head-h data (offset (lk&1)*8),
    // D = 2*S_h -> scale 0.125. Branchless; A/B share the k-slot map.
    stage_h(Wo, 128, 64, 0, panB, tid);           // B free (Wv1 consumed)
    const int dup = (lk & 1) * 8;
#pragma unroll 1
    for (int h = 0; h < 8; ++h) {
        bf16x8 aQ = *(const bf16x8*)(sQ + (m0 + lr) * 136 + h * 16 + dup);
        f32x4 sc[4];
#pragma unroll
        for (int nt = 0; nt < 4; ++nt) {
            bf16x8 bK = *(const bf16x8*)(sK + (nt * 16 + lr) * 136 + h * 16 + dup);
            f32x4 zz = {0.f, 0.f, 0.f, 0.f};
            sc[nt] = MFMA16(aQ, bK, zz);
        }
#pragma unroll
        for (int nt = 0; nt < 4; ++nt) {
            bool msk = (nt * 16 + lr) >= vld;
#pragma unroll
            for (int r = 0; r < 4; ++r) {
                float v0 = sc[nt][r] * 0.125f;
                sc[nt][r] = msk ? -1e9f : v0;
            }
        }
        float mx[4], sm[4];
#pragma unroll
        for (int r = 0; r < 4; ++r) {
            float m_ = fmaxf(fmaxf(sc[0][r], sc[1][r]), fmaxf(sc[2][r], sc[3][r]));
            m_ = fmaxf(m_, __shfl_xor(m_, 1));
            m_ = fmaxf(m_, __shfl_xor(m_, 2));
            m_ = fmaxf(m_, __shfl_xor(m_, 4));
            m_ = fmaxf(m_, __shfl_xor(m_, 8));
            mx[r] = m_; sm[r] = 0.f;
        }
#pragma unroll
        for (int nt = 0; nt < 4; ++nt)
#pragma unroll
            for (int r = 0; r < 4; ++r) {
                float e = __expf(sc[nt][r] - mx[r]);
                sc[nt][r] = e; sm[r] += e;
            }
#pragma unroll
        for (int r = 0; r < 4; ++r) {
            float s_ = sm[r];
            s_ += __shfl_xor(s_, 1); s_ += __shfl_xor(s_, 2);
            s_ += __shfl_xor(s_, 4); s_ += __shfl_xor(s_, 8);
            sm[r] = 1.f / s_;
        }
#pragma unroll
        for (int nt = 0; nt < 4; ++nt)
#pragma unroll
            for (int r = 0; r < 4; ++r)
                sAttn[(m0 + lk * 4 + r) * 72 + nt * 16 + lr] = f2bf(sc[nt][r] * sm[r]);
        CFENCE();   // P stores -> aP vector loads (wave-local)
        f32x4 cc = {0.f, 0.f, 0.f, 0.f};
#pragma unroll
        for (int ks = 0; ks < 2; ++ks) {
            bf16x8 aP = *(const bf16x8*)(sAttn + (m0 + lr) * 72 + ks * 32 + lk * 8);
            bf16x8 bV = *(const bf16x8*)(sVt + (h * 16 + lr) * 72 + ks * 32 + lk * 8);
            cc = MFMA16(aP, bV, cc);
        }
        // ctx in-place into sQ (head-h Q cols consumed; wave-local rows)
#pragma unroll
        for (int r = 0; r < 4; ++r)
            sQ[(m0 + lk * 4 + r) * 136 + h * 16 + lr] = f2bf(cc[r]);
    }
    CFENCE();            // ctx stores -> aC vector loads (wave-local)
    __syncthreads();     // publish Wo1(B); attention complete block-wide

    // ---- O-projection + residual(feat) + LN1 -------------------------------
    bf16x8 aC[4];
#pragma unroll
    for (int ks = 0; ks < 4; ++ks)
        aC[ks] = *(const bf16x8*)(sQ + (m0 + lr) * 136 + ks * 32 + lk * 8);
    f32x4 v8[8];
    {   // O0: gemm(A)=Wo0, no stage (Wo1 already in B)
        f32x4 acc[4] = {};
        gemm_h(aC, panA, lr, lk, acc);
#pragma unroll
        for (int nt = 0; nt < 4; ++nt) {
            int col = nt * 16 + lr; float bb = bo[col];
#pragma unroll
            for (int r = 0; r < 4; ++r)
                v8[nt][r] = acc[nt][r] + bb + fw[(m0 + lk * 4 + r) * 128 + col];
        }
        __syncthreads();   // A reads done (so O1 may stage into A)
    }
    {   // O1: gemm(B)=Wo1, stage W1_0->A
        stage_h(W1, 256, 0, 0, panA, tid);
        f32x4 acc[4] = {};
        gemm_h(aC, panB, lr, lk, acc);
#pragma unroll
        for (int nt = 0; nt < 4; ++nt) {
            int col = 64 + nt * 16 + lr; float bb = bo[col];
#pragma unroll
            for (int r = 0; r < 4; ++r)
                v8[4 + nt][r] = acc[nt][r] + bb + fw[(m0 + lk * 4 + r) * 128 + col];
        }
        __syncthreads();
    }
    float mu[4], rs[4];
    row_ln(v8, mu, rs);
    f32x4 srcv[8];                           // f32 src for FFN2 residual
#pragma unroll
    for (int nt = 0; nt < 8; ++nt) {
        int col = nt * 16 + lr;
        float gg = g1[col], bb = be1[col];
#pragma unroll
        for (int r = 0; r < 4; ++r) {
            float sv = (v8[nt][r] - mu[r]) * rs[r] * gg + bb;
            srcv[nt][r] = sv;
            sQ[(m0 + lk * 4 + r) * 136 + col] = f2bf(sv);     // wave-local rows
        }
    }
    CFENCE();
    bf16x8 aS[4];
#pragma unroll
    for (int ks = 0; ks < 4; ++ks)
        aS[ks] = *(const bf16x8*)(sQ + (m0 + lr) * 136 + ks * 32 + lk * 8);

    // ---- FFN1: relu(src@W1 + b1) -> sF1 (4 half-panels) --------------------
    // F0..F3 consume A,B,A,B; stage W1_1->B, W1_2->A, W1_3->B, W2_00->A.
#pragma unroll
    for (int hf = 0; hf < 4; ++hf) {
        u16* cur = (hf & 1) ? panB : panA;
        u16* nxt = (hf & 1) ? panA : panB;
        if (hf < 3) stage_h(W1, 256, (hf + 1) * 64, 0, nxt, tid);
        else        stage_h(W2, 128, 0, 0, nxt, tid);
        f32x4 f1a[4] = {};
        gemm_h(aS, cur, lr, lk, f1a);
#pragma unroll
        for (int nt = 0; nt < 4; ++nt) {
            int col = hf * 64 + nt * 16 + lr; float bb = b1[col];
#pragma unroll
            for (int r = 0; r < 4; ++r)
                sF1[(m0 + lk * 4 + r) * 264 + col] = f2bf(fmaxf(f1a[nt][r] + bb, 0.f));
        }
        __syncthreads();
    }

    // ---- FFN2: 4 half-panels (kh,nh) = (0,0),(0,1),(1,0),(1,1) -------------
    // F3 staged W2_00 -> A, so S0..S3 consume A,B,A,B.
    f32x4 oa[8] = {};
#pragma unroll
    for (int s = 0; s < 4; ++s) {
        u16* cur = (s & 1) ? panB : panA;
        u16* nxt = (s & 1) ? panA : panB;
        if (s < 3) {
            int ns = s + 1, nkh = ns >> 1, nnh = ns & 1;
            stage_h(W2, 128, nnh * 64, nkh * 128, nxt, tid);
        }
        int kh = s >> 1, nh = s & 1;
#pragma unroll
        for (int ks = 0; ks < 4; ++ks) {
            bf16x8 aF = *(const bf16x8*)(sF1 + (m0 + lr) * 264 + kh * 128 + ks * 32 + lk * 8);
#pragma unroll
            for (int nt = 0; nt < 4; ++nt) {
                bf16x8 b = *(const bf16x8*)(cur + (nt * 16 + lr) * 136 + ks * 32 + lk * 8);
                oa[nh * 4 + nt] = MFMA16(aF, b, oa[nh * 4 + nt]);
            }
        }
        if (s < 3) __syncthreads();
    }

    // ---- epilogue: bias + residual(src) + LN2 -> out ------------------------
#pragma unroll
    for (int nt = 0; nt < 8; ++nt) {
        int col = nt * 16 + lr; float bb = b2[col];
#pragma unroll
        for (int r = 0; r < 4; ++r)
            v8[nt][r] = oa[nt][r] + bb + srcv[nt][r];
    }
    row_ln(v8, mu, rs);
    float* ow = out + (size_t)w * 8192;
#pragma unroll
    for (int nt = 0; nt < 8; ++nt) {
        int col = nt * 16 + lr;
        float gg = g2[col], bb = be2[col];
#pragma unroll
        for (int r = 0; r < 4; ++r)
            ow[(m0 + lk * 4 + r) * 128 + col] = (v8[nt][r] - mu[r]) * rs[r] * gg + bb;
    }
}

extern "C" void kernel_launch(void* const* d_in, const int* in_sizes, int n_in,
                              void* d_out, int out_size, void* d_ws, size_t ws_size,
                              hipStream_t stream) {
    (void)in_sizes; (void)n_in; (void)out_size; (void)d_ws; (void)ws_size;
    const float* feat = (const float*)d_in[0];
    const float* pos  = (const float*)d_in[1];
    const unsigned char* mask = (const unsigned char*)d_in[2];
    const float* Wq = (const float*)d_in[3];  const float* bq = (const float*)d_in[4];
    const float* Wk = (const float*)d_in[5];  const float* bk = (const float*)d_in[6];
    const float* Wv = (const float*)d_in[7];  const float* bv = (const float*)d_in[8];
    const float* Wo = (const float*)d_in[9];  const float* bo = (const float*)d_in[10];
    const float* W1 = (const float*)d_in[11]; const float* b1 = (const float*)d_in[12];
    const float* W2 = (const float*)d_in[13]; const float* b2 = (const float*)d_in[14];
    const float* g1 = (const float*)d_in[15]; const float* be1 = (const float*)d_in[16];
    const float* g2 = (const float*)d_in[17]; const float* be2 = (const float*)d_in[18];

    enc_main<<<2048, 512, 0, stream>>>(feat, pos, mask,
                                       Wq, bq, Wk, bk, Wv, bv, Wo, bo,
                                       W1, b1, W2, b2, g1, be1, g2, be2,
                                       (float*)d_out);
}